// Round 1
// baseline (44.426 us; speedup 1.0000x reference)
//
#include <hip/hip_runtime.h>

#define FWHT_N 4096

static constexpr float FWHT_SCALE = 0.17677669529663687f; // 1/sqrt(32)

// In-register 16-point FWHT (4 butterfly stages, fully unrolled, static idx)
__device__ __forceinline__ void fwht16(float v[16]) {
#pragma unroll
  for (int s = 1; s < 16; s <<= 1) {
#pragma unroll
    for (int m = 0; m < 16; ++m) {
      if (!(m & s)) {
        const float a = v[m];
        const float b = v[m ^ s];
        v[m] = a + b;
        v[m ^ s] = a - b;
      }
    }
  }
}

// One block per row. 256 threads x 16 floats = 4096.
// 3 phases of in-register 16-pt FWHT over bit groups:
//   phase A: element bits {0,1} (j) and {10,11} (c)
//   phase B: element bits {2,3} (j') and {4,5} (c')
//   phase C: element bits {6,7} (j'') and {8,9} (c'')
// LDS exchanges between phases use skewed addressing idx + (idx>>5)
// -> all scalar LDS accesses are <=2 lanes/bank (conflict-free on CDNA4).
__global__ __launch_bounds__(256) void OnlineHadamard_kernel(
    const float* __restrict__ x, float* __restrict__ out) {
  __shared__ float lds[FWHT_N + FWHT_N / 32];  // 4224 floats = 16.5 KB

  const int t = threadIdx.x;
  const size_t row = blockIdx.x;
  const float* __restrict__ xr = x + row * FWHT_N;
  float* __restrict__ orow = out + row * FWHT_N;

  float v[16];

  // ---- Load: v[c*4+j] = x[c*1024 + t*4 + j]  (coalesced float4) ----
#pragma unroll
  for (int c = 0; c < 4; ++c) {
    const float4 f = *reinterpret_cast<const float4*>(xr + c * 1024 + t * 4);
    v[c * 4 + 0] = f.x;
    v[c * 4 + 1] = f.y;
    v[c * 4 + 2] = f.z;
    v[c * 4 + 3] = f.w;
  }

  // ---- Phase A: bits {0,1,10,11} ----
  fwht16(v);

  // ---- Exchange 1: write layout L1, read layout L2 ----
#pragma unroll
  for (int c = 0; c < 4; ++c) {
#pragma unroll
    for (int j = 0; j < 4; ++j) {
      const int idx = c * 1024 + t * 4 + j;
      lds[idx + (idx >> 5)] = v[c * 4 + j];
    }
  }
  __syncthreads();

  const int h = t >> 2;    // element bits 11..6
  const int lo2 = t & 3;   // element bits 1..0
#pragma unroll
  for (int c = 0; c < 4; ++c) {
#pragma unroll
    for (int j = 0; j < 4; ++j) {
      const int idx = h * 64 + c * 16 + j * 4 + lo2;
      v[c * 4 + j] = lds[idx + (idx >> 5)];
    }
  }

  // ---- Phase B: bits {2,3,4,5} ----
  fwht16(v);

  // ---- Exchange 2: write back to SAME slots (no barrier needed: slots are
  // private to this thread between the reads above and these writes) ----
#pragma unroll
  for (int c = 0; c < 4; ++c) {
#pragma unroll
    for (int j = 0; j < 4; ++j) {
      const int idx = h * 64 + c * 16 + j * 4 + lo2;
      lds[idx + (idx >> 5)] = v[c * 4 + j];
    }
  }
  __syncthreads();

  const int w = t >> 6;   // element bits 11..10
  const int l = t & 63;   // element bits 5..0
#pragma unroll
  for (int c = 0; c < 4; ++c) {
#pragma unroll
    for (int j = 0; j < 4; ++j) {
      const int idx = w * 1024 + c * 256 + j * 64 + l;
      v[c * 4 + j] = lds[idx + (idx >> 5)];
    }
  }

  // ---- Phase C: bits {6,7,8,9} ----
  fwht16(v);

  // ---- Store (scaled); lanes contiguous per (c,j) -> coalesced ----
#pragma unroll
  for (int c = 0; c < 4; ++c) {
#pragma unroll
    for (int j = 0; j < 4; ++j) {
      const int idx = w * 1024 + c * 256 + j * 64 + l;
      orow[idx] = v[c * 4 + j] * FWHT_SCALE;
    }
  }
}

extern "C" void kernel_launch(void* const* d_in, const int* in_sizes, int n_in,
                              void* d_out, int out_size, void* d_ws, size_t ws_size,
                              hipStream_t stream) {
  const float* x = (const float*)d_in[0];
  float* out = (float*)d_out;
  const int rows = out_size / FWHT_N;  // 8192
  OnlineHadamard_kernel<<<dim3(rows), dim3(256), 0, stream>>>(x, out);
}